// Round 3
// baseline (550.181 us; speedup 1.0000x reference)
//
#include <hip/hip_runtime.h>

typedef unsigned int u32;
typedef unsigned short u16;
using s16x8 = __attribute__((ext_vector_type(8))) short;   // 8 bf16 (4 VGPRs)
using f32x4 = __attribute__((ext_vector_type(4))) float;

static constexpr int NB = 512;     // batch
static constexpr int L  = 512;     // points per cloud
static constexpr int F  = 64;      // input features
static constexpr int H  = 128;     // hidden features
static constexpr float EPS = 1e-5f;
static const size_t NTOT = (size_t)NB * L * 2 * H;   // g tail offset in out

// ws layout: [0,32K) W-hi frags; [32K,64K) W-lo frags; [64K,64K+2K) counters
static constexpr size_t WS_LO   = 32768;
static constexpr size_t WS_CNT  = 65536;
static constexpr size_t WS_NEED = 67584;

// round-to-nearest-even fp32 -> bf16 bits
__device__ __forceinline__ u32 bf_rne(float f) {
    u32 u = __float_as_uint(f);
    return (u + 0x7fffu + ((u >> 16) & 1u)) >> 16;
}

#define GLD_LDS16(gsrc, ldst)                                                     \
    __builtin_amdgcn_global_load_lds(                                             \
        (const __attribute__((address_space(1))) void*)(gsrc),                    \
        (__attribute__((address_space(3))) void*)(ldst), 16, 0, 0)

// ---------------------------------------------------------------------------
// PREP: blocks 0-3 convert W into frag-ordered split-bf16 hi/lo in ws (once,
// instead of per-block in the GEMM). Blocks 4-7 zero the g tail (atomicMax
// target; harness poisons with 0xAA) and the per-cloud arrival counters.
// Frag order: group g (0..1023) = (t=g>>7, s=(g>>6)&1, ln=g&63);
//             element j: W[t*16+(ln&15)][s*32+(ln>>4)*8+j]
// ---------------------------------------------------------------------------
__global__ __launch_bounds__(256)
void kp_prep(const float* __restrict__ Wp, float* __restrict__ outp,
             char* __restrict__ ws)
{
    const int bx  = blockIdx.x;
    const int tid = threadIdx.x;
    if (bx < 4) {
        const int g  = bx * 256 + tid;
        const int t  = g >> 7;
        const int s  = (g >> 6) & 1;
        const int ln = g & 63;
        const int mm = ln & 15;
        const int qq = ln >> 4;
        const float* src = Wp + (t * 16 + mm) * F + s * 32 + qq * 8;
        const float4 a = *(const float4*)src;
        const float4 b = *(const float4*)(src + 4);
        const float xv[8] = {a.x, a.y, a.z, a.w, b.x, b.y, b.z, b.w};
        u32 hi[8], lo[8];
        #pragma unroll
        for (int j = 0; j < 8; ++j) {
            hi[j] = bf_rne(xv[j]);
            const float hf = __uint_as_float(hi[j] << 16);
            lo[j] = bf_rne(xv[j] - hf);
        }
        uint4 ph, pl;
        ph.x = hi[0] | (hi[1] << 16); ph.y = hi[2] | (hi[3] << 16);
        ph.z = hi[4] | (hi[5] << 16); ph.w = hi[6] | (hi[7] << 16);
        pl.x = lo[0] | (lo[1] << 16); pl.y = lo[2] | (lo[3] << 16);
        pl.z = lo[4] | (lo[5] << 16); pl.w = lo[6] | (lo[7] << 16);
        *(uint4*)(ws + (size_t)g * 16)         = ph;
        *(uint4*)(ws + WS_LO + (size_t)g * 16) = pl;
    } else {
        // zero g tail: 65536 floats = 16384 float4 over 1024 threads
        const int b2 = bx - 4;
        float* gt = outp + NTOT;
        const float4 z4 = {0.f, 0.f, 0.f, 0.f};
        #pragma unroll
        for (int i = 0; i < 16; ++i)
            *(float4*)(gt + ((size_t)(b2 * 256 + tid) + (size_t)i * 1024) * 4) = z4;
        if (bx == 4) {
            u32* cnt = (u32*)(ws + WS_CNT);
            cnt[tid]       = 0u;
            cnt[tid + 256] = 0u;
        }
    }
}

// ---------------------------------------------------------------------------
// MAIN: one block per (cloud n, 64-row chunk); 4 waves x 16 rows.
// W frags: ws -> LDS via global_load_lds width=16 (linear layout, no VALU).
// Split-bf16 MFMA GEMM -> +bias -> LayerNorm -> ReLU -> LDS-transposed
// coalesced y stores -> block masked-max -> atomicMax into g tail.
// Last-arriving block per cloud (device-scope counter) re-reads final g via
// the coherent atomic path and broadcasts it into the cloud's 512 row-halves,
// overlapping the rest of the grid's GEMM work (replaces k2).
// ---------------------------------------------------------------------------
__global__ __launch_bounds__(256)
void k1_main(const float* __restrict__ xp, const int* __restrict__ maskp,
             const float* __restrict__ bp, const float* __restrict__ gp,
             const float* __restrict__ betap, float* __restrict__ outp,
             char* __restrict__ ws)
{
    __shared__ __align__(16) char smem[36864];
    u16*   whi  = (u16*)smem;                 // [0,16K): B-frag W hi
    u16*   wlo  = (u16*)(smem + 16384);       // [16K,32K): B-frag W lo
    float* tb   = (float*)smem;               // [0,33792): 64 x 132 floats (aliases whi/wlo)
    float* gsh  = (float*)(smem + 33792);     // [4][128] per-wave max partials
    float* gfin = (float*)(smem + 35840);     // [128] final g (epilogue block)
    int*   bflg = (int*)(smem + 36352);       // arrival-order broadcast

    const int bx    = blockIdx.x;
    const int n     = bx >> 3;
    const int chunk = bx & 7;
    const int tid   = threadIdx.x;
    const int w     = tid >> 6;
    const int lane  = tid & 63;
    const int m     = lane & 15;
    const int q     = lane >> 4;

    // ---- A fragments first (issue loads early): x rows rb..rb+15, hi/lo split
    const int rb = n * L + chunk * 64 + w * 16;
    const float* xs0 = xp + (size_t)(rb + m) * F + q * 8;
    const float4 a0 = *(const float4*)xs0;
    const float4 b0 = *(const float4*)(xs0 + 4);
    const float4 a1 = *(const float4*)(xs0 + 32);
    const float4 b1 = *(const float4*)(xs0 + 36);

    // ---- W frags: ws -> LDS, 16B per lane, wave-uniform dest base
    #pragma unroll
    for (int c = 0; c < 4; ++c) {
        const int cc = c * 4 + w;
        GLD_LDS16(ws + ((size_t)cc * 64 + lane) * 16,         smem + cc * 1024);
        GLD_LDS16(ws + WS_LO + ((size_t)cc * 64 + lane) * 16, smem + 16384 + cc * 1024);
    }

    s16x8 Ahi[2], Alo[2];
    {
        const float xv0[8] = {a0.x, a0.y, a0.z, a0.w, b0.x, b0.y, b0.z, b0.w};
        const float xv1[8] = {a1.x, a1.y, a1.z, a1.w, b1.x, b1.y, b1.z, b1.w};
        #pragma unroll
        for (int j = 0; j < 8; ++j) {
            u32 hb = bf_rne(xv0[j]);
            Ahi[0][j] = (short)hb;
            Alo[0][j] = (short)bf_rne(xv0[j] - __uint_as_float(hb << 16));
            hb = bf_rne(xv1[j]);
            Ahi[1][j] = (short)hb;
            Alo[1][j] = (short)bf_rne(xv1[j] - __uint_as_float(hb << 16));
        }
    }
    __syncthreads();

    // ---- MFMA: 8 h-tiles x 2 k-steps x 3 split terms
    f32x4 acc[8] = {};
    #pragma unroll
    for (int t = 0; t < 8; ++t) {
        #pragma unroll
        for (int s = 0; s < 2; ++s) {
            const s16x8 Bh = *(const s16x8*)&whi[((t * 2 + s) * 64 + lane) * 8];
            const s16x8 Bl = *(const s16x8*)&wlo[((t * 2 + s) * 64 + lane) * 8];
            acc[t] = __builtin_amdgcn_mfma_f32_16x16x32_bf16(Ahi[s], Bh, acc[t], 0, 0, 0);
            acc[t] = __builtin_amdgcn_mfma_f32_16x16x32_bf16(Alo[s], Bh, acc[t], 0, 0, 0);
            acc[t] = __builtin_amdgcn_mfma_f32_16x16x32_bf16(Ahi[s], Bl, acc[t], 0, 0, 0);
        }
    }

    // ---- per-column params (h = t*16 + m); L1/L2-hot scalar loads
    float bias[8], gam[8], bet[8];
    #pragma unroll
    for (int t = 0; t < 8; ++t) {
        const int h = t * 16 + m;
        bias[t] = bp[h];
        gam[t]  = gp[h];
        bet[t]  = betap[h];
    }
    #pragma unroll
    for (int t = 0; t < 8; ++t)
        #pragma unroll
        for (int r = 0; r < 4; ++r)
            acc[t][r] += bias[t];

    // ---- LayerNorm stats. C/D layout: col=lane&15, row=q*4+reg.
    float sum[4] = {0, 0, 0, 0}, sq[4] = {0, 0, 0, 0};
    #pragma unroll
    for (int t = 0; t < 8; ++t)
        #pragma unroll
        for (int r = 0; r < 4; ++r) {
            const float v = acc[t][r];
            sum[r] += v; sq[r] += v * v;
        }
    #pragma unroll
    for (int r = 0; r < 4; ++r) {
        #pragma unroll
        for (int o = 1; o < 16; o <<= 1) {
            sum[r] += __shfl_xor(sum[r], o);
            sq[r]  += __shfl_xor(sq[r],  o);
        }
    }
    float mu[4], rs[4];
    #pragma unroll
    for (int r = 0; r < 4; ++r) {
        mu[r] = sum[r] * (1.0f / 128.0f);
        const float var = sq[r] * (1.0f / 128.0f) - mu[r] * mu[r];
        rs[r] = rsqrtf(var + EPS);
    }

    int mk[4];
    #pragma unroll
    for (int r = 0; r < 4; ++r) mk[r] = maskp[rb + q * 4 + r];

    // ---- normalize, relu -> y in regs; masked max in regs
    float gmax[8];
    #pragma unroll
    for (int t = 0; t < 8; ++t) {
        float gm = 0.0f;
        #pragma unroll
        for (int r = 0; r < 4; ++r) {
            float y = (acc[t][r] - mu[r]) * rs[r] * gam[t] + bet[t];
            y = fmaxf(y, 0.0f);
            acc[t][r] = y;
            if (mk[r] != 0) gm = fmaxf(gm, y);
        }
        gmax[t] = gm;
    }

    // ---- transpose through LDS (whi/wlo dead for all waves after this sync)
    __syncthreads();
    #pragma unroll
    for (int t = 0; t < 8; ++t)
        #pragma unroll
        for (int r = 0; r < 4; ++r)
            tb[(w * 16 + q * 4 + r) * 132 + t * 16 + m] = acc[t][r];
    __syncthreads();

    // ---- store 64 rows x 512B first-halves, fully coalesced
    {
        const int rr0 = tid >> 5;          // 0..7
        const int c   = tid & 31;          // float4 index within row-half
        const size_t growbase = (size_t)n * L + chunk * 64;
        #pragma unroll
        for (int i = 0; i < 8; ++i) {
            const int rr = i * 8 + rr0;
            const float4 v = *(const float4*)&tb[rr * 132 + c * 4];
            *(float4*)(outp + (growbase + rr) * (2 * H) + c * 4) = v;
        }
    }

    // ---- per-wave masked-max partials -> block reduce -> atomicMax to tail
    #pragma unroll
    for (int t = 0; t < 8; ++t) {
        float gm = gmax[t];
        gm = fmaxf(gm, __shfl_xor(gm, 16));
        gm = fmaxf(gm, __shfl_xor(gm, 32));
        if (q == 0) gsh[w * H + t * 16 + m] = gm;
    }
    __syncthreads();
    if (tid < H) {
        const float mx = fmaxf(fmaxf(gsh[0 * H + tid], gsh[1 * H + tid]),
                               fmaxf(gsh[2 * H + tid], gsh[3 * H + tid]));
        atomicMax((u32*)(outp + NTOT + (size_t)n * H + tid), __float_as_uint(mx));
    }
    __syncthreads();   // barrier drains the atomicMax ops (vmcnt(0) before s_barrier)

    // ---- arrival counter: 8th arriver broadcasts this cloud's g
    if (tid == 0) {
        __threadfence();                                  // release our contributions
        *bflg = (int)atomicAdd((u32*)(ws + WS_CNT) + n, 1u);
    }
    __syncthreads();
    if (*bflg == 7) {
        // all 8 chunks' atomicMax complete; read final g via coherent atomic path
        if (tid < H) {
            const u32 bits = atomicMax((u32*)(outp + NTOT + (size_t)n * H + tid), 0u);
            gfin[tid] = __uint_as_float(bits);
        }
        __syncthreads();
        const int tc = tid & 31;
        const int tr = tid >> 5;
        const float4 g4 = *(const float4*)&gfin[tc * 4];
        float* dst = outp + (size_t)n * L * (2 * H) + H + tc * 4;
        #pragma unroll 8
        for (int i = 0; i < 64; ++i) {
            *(float4*)(dst + (size_t)(tr + i * 8) * (2 * H)) = g4;
        }
    }
}

// ===========================================================================
// Fallback path (verified round-2 kernels) if ws_size is too small.
// ===========================================================================
__global__ __launch_bounds__(256)
void k0_init(float* __restrict__ outp)
{
    const int i = blockIdx.x * 256 + threadIdx.x;
    if (i < NB * H) outp[NTOT + i] = 0.0f;
}

__global__ __launch_bounds__(256)
void k1_gemm_ln(const float* __restrict__ xp, const int* __restrict__ maskp,
                const float* __restrict__ Wp, const float* __restrict__ bp,
                const float* __restrict__ gp, const float* __restrict__ betap,
                float* __restrict__ outp)
{
    __shared__ __align__(16) char smem[35840];
    u16*   whi = (u16*)smem;
    u16*   wlo = (u16*)(smem + 16384);
    float* tb  = (float*)smem;
    float* gsh = (float*)(smem + 33792);

    const int bx    = blockIdx.x;
    const int n     = bx >> 3;
    const int chunk = bx & 7;
    const int tid   = threadIdx.x;
    const int w     = tid >> 6;
    const int lane  = tid & 63;
    const int m     = lane & 15;
    const int q     = lane >> 4;

    #pragma unroll
    for (int it = 0; it < 4; ++it) {
        const int g  = it * 256 + tid;
        const int t  = g >> 7;
        const int s  = (g >> 6) & 1;
        const int ln = g & 63;
        const int mm = ln & 15;
        const int qq = ln >> 4;
        const float* src = Wp + (t * 16 + mm) * F + s * 32 + qq * 8;
        const float4 a = *(const float4*)src;
        const float4 b = *(const float4*)(src + 4);
        const float xv[8] = {a.x, a.y, a.z, a.w, b.x, b.y, b.z, b.w};
        u32 hi[8], lo[8];
        #pragma unroll
        for (int j = 0; j < 8; ++j) {
            hi[j] = bf_rne(xv[j]);
            const float hf = __uint_as_float(hi[j] << 16);
            lo[j] = bf_rne(xv[j] - hf);
        }
        uint4 ph, pl;
        ph.x = hi[0] | (hi[1] << 16); ph.y = hi[2] | (hi[3] << 16);
        ph.z = hi[4] | (hi[5] << 16); ph.w = hi[6] | (hi[7] << 16);
        pl.x = lo[0] | (lo[1] << 16); pl.y = lo[2] | (lo[3] << 16);
        pl.z = lo[4] | (lo[5] << 16); pl.w = lo[6] | (lo[7] << 16);
        *(uint4*)&whi[g * 8] = ph;
        *(uint4*)&wlo[g * 8] = pl;
    }

    const int rb = n * L + chunk * 64 + w * 16;
    s16x8 Ahi[2], Alo[2];
    #pragma unroll
    for (int s = 0; s < 2; ++s) {
        const float* xs = xp + (size_t)(rb + m) * F + s * 32 + q * 8;
        const float4 a = *(const float4*)xs;
        const float4 b = *(const float4*)(xs + 4);
        const float xv[8] = {a.x, a.y, a.z, a.w, b.x, b.y, b.z, b.w};
        #pragma unroll
        for (int j = 0; j < 8; ++j) {
            const u32 hb = bf_rne(xv[j]);
            const float hf = __uint_as_float(hb << 16);
            Ahi[s][j] = (short)hb;
            Alo[s][j] = (short)bf_rne(xv[j] - hf);
        }
    }
    __syncthreads();

    f32x4 acc[8] = {};
    #pragma unroll
    for (int t = 0; t < 8; ++t) {
        #pragma unroll
        for (int s = 0; s < 2; ++s) {
            const s16x8 Bh = *(const s16x8*)&whi[((t * 2 + s) * 64 + lane) * 8];
            const s16x8 Bl = *(const s16x8*)&wlo[((t * 2 + s) * 64 + lane) * 8];
            acc[t] = __builtin_amdgcn_mfma_f32_16x16x32_bf16(Ahi[s], Bh, acc[t], 0, 0, 0);
            acc[t] = __builtin_amdgcn_mfma_f32_16x16x32_bf16(Alo[s], Bh, acc[t], 0, 0, 0);
            acc[t] = __builtin_amdgcn_mfma_f32_16x16x32_bf16(Ahi[s], Bl, acc[t], 0, 0, 0);
        }
    }

    float bias[8], gam[8], bet[8];
    #pragma unroll
    for (int t = 0; t < 8; ++t) {
        const int h = t * 16 + m;
        bias[t] = bp[h];
        gam[t]  = gp[h];
        bet[t]  = betap[h];
    }
    #pragma unroll
    for (int t = 0; t < 8; ++t)
        #pragma unroll
        for (int r = 0; r < 4; ++r)
            acc[t][r] += bias[t];

    float sum[4] = {0, 0, 0, 0}, sq[4] = {0, 0, 0, 0};
    #pragma unroll
    for (int t = 0; t < 8; ++t)
        #pragma unroll
        for (int r = 0; r < 4; ++r) {
            const float v = acc[t][r];
            sum[r] += v; sq[r] += v * v;
        }
    #pragma unroll
    for (int r = 0; r < 4; ++r) {
        #pragma unroll
        for (int o = 1; o < 16; o <<= 1) {
            sum[r] += __shfl_xor(sum[r], o);
            sq[r]  += __shfl_xor(sq[r],  o);
        }
    }
    float mu[4], rs[4];
    #pragma unroll
    for (int r = 0; r < 4; ++r) {
        mu[r] = sum[r] * (1.0f / 128.0f);
        const float var = sq[r] * (1.0f / 128.0f) - mu[r] * mu[r];
        rs[r] = rsqrtf(var + EPS);
    }

    int mk[4];
    #pragma unroll
    for (int r = 0; r < 4; ++r) mk[r] = maskp[rb + q * 4 + r];

    float gmax[8];
    #pragma unroll
    for (int t = 0; t < 8; ++t) {
        float gm = 0.0f;
        #pragma unroll
        for (int r = 0; r < 4; ++r) {
            float y = (acc[t][r] - mu[r]) * rs[r] * gam[t] + bet[t];
            y = fmaxf(y, 0.0f);
            acc[t][r] = y;
            if (mk[r] != 0) gm = fmaxf(gm, y);
        }
        gmax[t] = gm;
    }

    __syncthreads();
    #pragma unroll
    for (int t = 0; t < 8; ++t)
        #pragma unroll
        for (int r = 0; r < 4; ++r)
            tb[(w * 16 + q * 4 + r) * 132 + t * 16 + m] = acc[t][r];
    __syncthreads();

    {
        const int rr0 = tid >> 5;
        const int c   = tid & 31;
        const size_t growbase = (size_t)n * L + chunk * 64;
        #pragma unroll
        for (int i = 0; i < 8; ++i) {
            const int rr = i * 8 + rr0;
            const float4 v = *(const float4*)&tb[rr * 132 + c * 4];
            *(float4*)(outp + (growbase + rr) * (2 * H) + c * 4) = v;
        }
    }

    #pragma unroll
    for (int t = 0; t < 8; ++t) {
        float gm = gmax[t];
        gm = fmaxf(gm, __shfl_xor(gm, 16));
        gm = fmaxf(gm, __shfl_xor(gm, 32));
        if (q == 0) gsh[w * H + t * 16 + m] = gm;
    }
    __syncthreads();
    if (tid < H) {
        const float mx = fmaxf(fmaxf(gsh[0 * H + tid], gsh[1 * H + tid]),
                               fmaxf(gsh[2 * H + tid], gsh[3 * H + tid]));
        atomicMax((u32*)(outp + NTOT + (size_t)n * H + tid), __float_as_uint(mx));
    }
}

__global__ __launch_bounds__(256)
void k2_bcast(float* __restrict__ outp)
{
    const int bx  = blockIdx.x;
    const int n   = bx >> 3;
    const int c2  = bx & 7;
    const int tid = threadIdx.x;
    const int tc  = tid & 31;
    const int tr  = tid >> 5;
    const int h0  = tc * 4;

    const float4 g4 = *(const float4*)(outp + NTOT + (size_t)n * H + h0);

    #pragma unroll
    for (int ri = 0; ri < 8; ++ri) {
        const int l = c2 * 64 + tr * 8 + ri;
        *(float4*)(outp + ((size_t)n * L + l) * (2 * H) + H + h0) = g4;
    }
}

extern "C" void kernel_launch(void* const* d_in, const int* in_sizes, int n_in,
                              void* d_out, int out_size, void* d_ws, size_t ws_size,
                              hipStream_t stream)
{
    (void)in_sizes; (void)n_in; (void)out_size;
    const float* x     = (const float*)d_in[0];
    const int*   mask  = (const int*)d_in[1];
    const float* W     = (const float*)d_in[2];
    const float* b     = (const float*)d_in[3];
    const float* gamma = (const float*)d_in[4];
    const float* beta  = (const float*)d_in[5];
    float* out = (float*)d_out;

    if (d_ws != nullptr && ws_size >= WS_NEED) {
        kp_prep<<<dim3(8), dim3(256), 0, stream>>>(W, out, (char*)d_ws);
        k1_main<<<dim3(NB * 8), dim3(256), 0, stream>>>(
            x, mask, b, gamma, beta, out, (char*)d_ws);
    } else {
        k0_init<<<dim3((NB * H + 255) / 256), dim3(256), 0, stream>>>(out);
        k1_gemm_ln<<<dim3(NB * 8), dim3(256), 0, stream>>>(
            x, mask, W, b, gamma, beta, out);
        k2_bcast<<<dim3(NB * 8), dim3(256), 0, stream>>>(out);
    }
}

// Round 4
// 368.488 us; speedup vs baseline: 1.4931x; 1.4931x over previous
//
#include <hip/hip_runtime.h>

typedef unsigned int u32;
typedef unsigned short u16;
using s16x8 = __attribute__((ext_vector_type(8))) short;   // 8 bf16 (4 VGPRs)
using f32x4 = __attribute__((ext_vector_type(4))) float;

static constexpr int NB = 512;     // batch
static constexpr int L  = 512;     // points per cloud
static constexpr int F  = 64;      // input features
static constexpr int H  = 128;     // hidden features
static constexpr float EPS = 1e-5f;
static const size_t NTOT = (size_t)NB * L * 2 * H;   // g tail offset in out

// ws layout: [0,32K) W-hi frags; [32K,64K) W-lo frags; [64K,64K+2K) counters
static constexpr size_t WS_LO   = 32768;
static constexpr size_t WS_CNT  = 65536;
static constexpr size_t WS_NEED = 67584;

// round-to-nearest-even fp32 -> bf16 bits
__device__ __forceinline__ u32 bf_rne(float f) {
    u32 u = __float_as_uint(f);
    return (u + 0x7fffu + ((u >> 16) & 1u)) >> 16;
}

#define GLD_LDS16(gsrc, ldst)                                                     \
    __builtin_amdgcn_global_load_lds(                                             \
        (const __attribute__((address_space(1))) void*)(gsrc),                    \
        (__attribute__((address_space(3))) void*)(ldst), 16, 0, 0)

// ---------------------------------------------------------------------------
// PREP: blocks 0-3 convert W into frag-ordered split-bf16 hi/lo in ws (once,
// instead of per-block in the GEMM). Blocks 4-7 zero the g tail (atomicMax
// target; harness poisons with 0xAA) and the per-cloud arrival counters.
// Frag order: group g (0..1023) = (t=g>>7, s=(g>>6)&1, ln=g&63);
//             element j: W[t*16+(ln&15)][s*32+(ln>>4)*8+j]
// ---------------------------------------------------------------------------
__global__ __launch_bounds__(256)
void kp_prep(const float* __restrict__ Wp, float* __restrict__ outp,
             char* __restrict__ ws)
{
    const int bx  = blockIdx.x;
    const int tid = threadIdx.x;
    if (bx < 4) {
        const int g  = bx * 256 + tid;
        const int t  = g >> 7;
        const int s  = (g >> 6) & 1;
        const int ln = g & 63;
        const int mm = ln & 15;
        const int qq = ln >> 4;
        const float* src = Wp + (t * 16 + mm) * F + s * 32 + qq * 8;
        const float4 a = *(const float4*)src;
        const float4 b = *(const float4*)(src + 4);
        const float xv[8] = {a.x, a.y, a.z, a.w, b.x, b.y, b.z, b.w};
        u32 hi[8], lo[8];
        #pragma unroll
        for (int j = 0; j < 8; ++j) {
            hi[j] = bf_rne(xv[j]);
            const float hf = __uint_as_float(hi[j] << 16);
            lo[j] = bf_rne(xv[j] - hf);
        }
        uint4 ph, pl;
        ph.x = hi[0] | (hi[1] << 16); ph.y = hi[2] | (hi[3] << 16);
        ph.z = hi[4] | (hi[5] << 16); ph.w = hi[6] | (hi[7] << 16);
        pl.x = lo[0] | (lo[1] << 16); pl.y = lo[2] | (lo[3] << 16);
        pl.z = lo[4] | (lo[5] << 16); pl.w = lo[6] | (lo[7] << 16);
        *(uint4*)(ws + (size_t)g * 16)         = ph;
        *(uint4*)(ws + WS_LO + (size_t)g * 16) = pl;
    } else {
        // zero g tail: 65536 floats = 16384 float4 over 1024 threads
        const int b2 = bx - 4;
        float* gt = outp + NTOT;
        const float4 z4 = {0.f, 0.f, 0.f, 0.f};
        #pragma unroll
        for (int i = 0; i < 16; ++i)
            *(float4*)(gt + ((size_t)(b2 * 256 + tid) + (size_t)i * 1024) * 4) = z4;
        if (bx == 4) {
            u32* cnt = (u32*)(ws + WS_CNT);
            cnt[tid]       = 0u;
            cnt[tid + 256] = 0u;
        }
    }
}

// ---------------------------------------------------------------------------
// MAIN: one block per (cloud n, 64-row chunk); 4 waves x 16 rows.
// W frags: ws -> LDS via global_load_lds width=16 (linear layout, no VALU).
// Split-bf16 MFMA GEMM -> +bias -> LayerNorm -> ReLU -> LDS-transposed
// coalesced y stores -> block masked-max -> atomicMax into g tail.
// Last-arriving block per cloud broadcasts the final g (replaces k2).
// ORDERING (no __threadfence — the round-3 fence forced a per-block L2
// writeback, cratering the whole grid): __syncthreads() emits
// s_waitcnt vmcnt(0) before s_barrier, draining the device-scope atomicMax
// ops, which are performed at the LLC coherence point. So by the time tid 0
// bumps the arrival counter (also an LLC atomic), this block's max
// contributions are globally visible. The 8th arriver re-reads final g via
// returning atomics at the same coherence point.
// ---------------------------------------------------------------------------
__global__ __launch_bounds__(256)
void k1_main(const float* __restrict__ xp, const int* __restrict__ maskp,
             const float* __restrict__ bp, const float* __restrict__ gp,
             const float* __restrict__ betap, float* __restrict__ outp,
             char* __restrict__ ws)
{
    __shared__ __align__(16) char smem[36864];
    u16*   whi  = (u16*)smem;                 // [0,16K): B-frag W hi
    u16*   wlo  = (u16*)(smem + 16384);       // [16K,32K): B-frag W lo
    float* tb   = (float*)smem;               // [0,33792): 64 x 132 floats (aliases whi/wlo)
    float* gsh  = (float*)(smem + 33792);     // [4][128] per-wave max partials
    float* gfin = (float*)(smem + 35840);     // [128] final g (epilogue block)
    int*   bflg = (int*)(smem + 36352);       // arrival-order broadcast

    const int bx    = blockIdx.x;
    const int n     = bx >> 3;
    const int chunk = bx & 7;
    const int tid   = threadIdx.x;
    const int w     = tid >> 6;
    const int lane  = tid & 63;
    const int m     = lane & 15;
    const int q     = lane >> 4;

    // ---- A fragments first (issue loads early): x rows rb..rb+15, hi/lo split
    const int rb = n * L + chunk * 64 + w * 16;
    const float* xs0 = xp + (size_t)(rb + m) * F + q * 8;
    const float4 a0 = *(const float4*)xs0;
    const float4 b0 = *(const float4*)(xs0 + 4);
    const float4 a1 = *(const float4*)(xs0 + 32);
    const float4 b1 = *(const float4*)(xs0 + 36);

    // ---- W frags: ws -> LDS, 16B per lane, wave-uniform dest base
    #pragma unroll
    for (int c = 0; c < 4; ++c) {
        const int cc = c * 4 + w;
        GLD_LDS16(ws + ((size_t)cc * 64 + lane) * 16,         smem + cc * 1024);
        GLD_LDS16(ws + WS_LO + ((size_t)cc * 64 + lane) * 16, smem + 16384 + cc * 1024);
    }

    s16x8 Ahi[2], Alo[2];
    {
        const float xv0[8] = {a0.x, a0.y, a0.z, a0.w, b0.x, b0.y, b0.z, b0.w};
        const float xv1[8] = {a1.x, a1.y, a1.z, a1.w, b1.x, b1.y, b1.z, b1.w};
        #pragma unroll
        for (int j = 0; j < 8; ++j) {
            u32 hb = bf_rne(xv0[j]);
            Ahi[0][j] = (short)hb;
            Alo[0][j] = (short)bf_rne(xv0[j] - __uint_as_float(hb << 16));
            hb = bf_rne(xv1[j]);
            Ahi[1][j] = (short)hb;
            Alo[1][j] = (short)bf_rne(xv1[j] - __uint_as_float(hb << 16));
        }
    }
    __syncthreads();

    // ---- MFMA: 8 h-tiles x 2 k-steps x 3 split terms
    f32x4 acc[8] = {};
    #pragma unroll
    for (int t = 0; t < 8; ++t) {
        #pragma unroll
        for (int s = 0; s < 2; ++s) {
            const s16x8 Bh = *(const s16x8*)&whi[((t * 2 + s) * 64 + lane) * 8];
            const s16x8 Bl = *(const s16x8*)&wlo[((t * 2 + s) * 64 + lane) * 8];
            acc[t] = __builtin_amdgcn_mfma_f32_16x16x32_bf16(Ahi[s], Bh, acc[t], 0, 0, 0);
            acc[t] = __builtin_amdgcn_mfma_f32_16x16x32_bf16(Alo[s], Bh, acc[t], 0, 0, 0);
            acc[t] = __builtin_amdgcn_mfma_f32_16x16x32_bf16(Ahi[s], Bl, acc[t], 0, 0, 0);
        }
    }

    // ---- per-column params (h = t*16 + m); L1/L2-hot scalar loads
    float bias[8], gam[8], bet[8];
    #pragma unroll
    for (int t = 0; t < 8; ++t) {
        const int h = t * 16 + m;
        bias[t] = bp[h];
        gam[t]  = gp[h];
        bet[t]  = betap[h];
    }
    #pragma unroll
    for (int t = 0; t < 8; ++t)
        #pragma unroll
        for (int r = 0; r < 4; ++r)
            acc[t][r] += bias[t];

    // ---- LayerNorm stats. C/D layout: col=lane&15, row=q*4+reg.
    float sum[4] = {0, 0, 0, 0}, sq[4] = {0, 0, 0, 0};
    #pragma unroll
    for (int t = 0; t < 8; ++t)
        #pragma unroll
        for (int r = 0; r < 4; ++r) {
            const float v = acc[t][r];
            sum[r] += v; sq[r] += v * v;
        }
    #pragma unroll
    for (int r = 0; r < 4; ++r) {
        #pragma unroll
        for (int o = 1; o < 16; o <<= 1) {
            sum[r] += __shfl_xor(sum[r], o);
            sq[r]  += __shfl_xor(sq[r],  o);
        }
    }
    float mu[4], rs[4];
    #pragma unroll
    for (int r = 0; r < 4; ++r) {
        mu[r] = sum[r] * (1.0f / 128.0f);
        const float var = sq[r] * (1.0f / 128.0f) - mu[r] * mu[r];
        rs[r] = rsqrtf(var + EPS);
    }

    int mk[4];
    #pragma unroll
    for (int r = 0; r < 4; ++r) mk[r] = maskp[rb + q * 4 + r];

    // ---- normalize, relu -> y in regs; masked max in regs
    float gmax[8];
    #pragma unroll
    for (int t = 0; t < 8; ++t) {
        float gm = 0.0f;
        #pragma unroll
        for (int r = 0; r < 4; ++r) {
            float y = (acc[t][r] - mu[r]) * rs[r] * gam[t] + bet[t];
            y = fmaxf(y, 0.0f);
            acc[t][r] = y;
            if (mk[r] != 0) gm = fmaxf(gm, y);
        }
        gmax[t] = gm;
    }

    // ---- transpose through LDS (whi/wlo dead for all waves after this sync)
    __syncthreads();
    #pragma unroll
    for (int t = 0; t < 8; ++t)
        #pragma unroll
        for (int r = 0; r < 4; ++r)
            tb[(w * 16 + q * 4 + r) * 132 + t * 16 + m] = acc[t][r];
    __syncthreads();

    // ---- store 64 rows x 512B first-halves, fully coalesced
    {
        const int rr0 = tid >> 5;          // 0..7
        const int c   = tid & 31;          // float4 index within row-half
        const size_t growbase = (size_t)n * L + chunk * 64;
        #pragma unroll
        for (int i = 0; i < 8; ++i) {
            const int rr = i * 8 + rr0;
            const float4 v = *(const float4*)&tb[rr * 132 + c * 4];
            *(float4*)(outp + (growbase + rr) * (2 * H) + c * 4) = v;
        }
    }

    // ---- per-wave masked-max partials -> block reduce -> atomicMax to tail
    #pragma unroll
    for (int t = 0; t < 8; ++t) {
        float gm = gmax[t];
        gm = fmaxf(gm, __shfl_xor(gm, 16));
        gm = fmaxf(gm, __shfl_xor(gm, 32));
        if (q == 0) gsh[w * H + t * 16 + m] = gm;
    }
    __syncthreads();
    if (tid < H) {
        const float mx = fmaxf(fmaxf(gsh[0 * H + tid], gsh[1 * H + tid]),
                               fmaxf(gsh[2 * H + tid], gsh[3 * H + tid]));
        atomicMax((u32*)(outp + NTOT + (size_t)n * H + tid), __float_as_uint(mx));
    }
    // barrier emits s_waitcnt vmcnt(0) -> our atomicMax ops are performed at
    // the LLC before any thread proceeds (release ordering without L2 flush)
    __syncthreads();

    // ---- arrival counter: 8th arriver broadcasts this cloud's g
    if (tid == 0)
        *bflg = (int)atomicAdd((u32*)(ws + WS_CNT) + n, 1u);
    __syncthreads();
    if (*bflg == 7) {
        // all 8 chunks' atomicMax complete; read final g via coherent atomic path
        if (tid < H) {
            const u32 bits = atomicMax((u32*)(outp + NTOT + (size_t)n * H + tid), 0u);
            gfin[tid] = __uint_as_float(bits);
        }
        __syncthreads();
        const int tc = tid & 31;
        const int tr = tid >> 5;
        const float4 g4 = *(const float4*)&gfin[tc * 4];
        float* dst = outp + (size_t)n * L * (2 * H) + H + tc * 4;
        #pragma unroll 8
        for (int i = 0; i < 64; ++i) {
            *(float4*)(dst + (size_t)(tr + i * 8) * (2 * H)) = g4;
        }
    }
}

// ===========================================================================
// Fallback path (verified round-2 kernels) if ws_size is too small.
// ===========================================================================
__global__ __launch_bounds__(256)
void k0_init(float* __restrict__ outp)
{
    const int i = blockIdx.x * 256 + threadIdx.x;
    if (i < NB * H) outp[NTOT + i] = 0.0f;
}

__global__ __launch_bounds__(256)
void k1_gemm_ln(const float* __restrict__ xp, const int* __restrict__ maskp,
                const float* __restrict__ Wp, const float* __restrict__ bp,
                const float* __restrict__ gp, const float* __restrict__ betap,
                float* __restrict__ outp)
{
    __shared__ __align__(16) char smem[35840];
    u16*   whi = (u16*)smem;
    u16*   wlo = (u16*)(smem + 16384);
    float* tb  = (float*)smem;
    float* gsh = (float*)(smem + 33792);

    const int bx    = blockIdx.x;
    const int n     = bx >> 3;
    const int chunk = bx & 7;
    const int tid   = threadIdx.x;
    const int w     = tid >> 6;
    const int lane  = tid & 63;
    const int m     = lane & 15;
    const int q     = lane >> 4;

    #pragma unroll
    for (int it = 0; it < 4; ++it) {
        const int g  = it * 256 + tid;
        const int t  = g >> 7;
        const int s  = (g >> 6) & 1;
        const int ln = g & 63;
        const int mm = ln & 15;
        const int qq = ln >> 4;
        const float* src = Wp + (t * 16 + mm) * F + s * 32 + qq * 8;
        const float4 a = *(const float4*)src;
        const float4 b = *(const float4*)(src + 4);
        const float xv[8] = {a.x, a.y, a.z, a.w, b.x, b.y, b.z, b.w};
        u32 hi[8], lo[8];
        #pragma unroll
        for (int j = 0; j < 8; ++j) {
            hi[j] = bf_rne(xv[j]);
            const float hf = __uint_as_float(hi[j] << 16);
            lo[j] = bf_rne(xv[j] - hf);
        }
        uint4 ph, pl;
        ph.x = hi[0] | (hi[1] << 16); ph.y = hi[2] | (hi[3] << 16);
        ph.z = hi[4] | (hi[5] << 16); ph.w = hi[6] | (hi[7] << 16);
        pl.x = lo[0] | (lo[1] << 16); pl.y = lo[2] | (lo[3] << 16);
        pl.z = lo[4] | (lo[5] << 16); pl.w = lo[6] | (lo[7] << 16);
        *(uint4*)&whi[g * 8] = ph;
        *(uint4*)&wlo[g * 8] = pl;
    }

    const int rb = n * L + chunk * 64 + w * 16;
    s16x8 Ahi[2], Alo[2];
    #pragma unroll
    for (int s = 0; s < 2; ++s) {
        const float* xs = xp + (size_t)(rb + m) * F + s * 32 + q * 8;
        const float4 a = *(const float4*)xs;
        const float4 b = *(const float4*)(xs + 4);
        const float xv[8] = {a.x, a.y, a.z, a.w, b.x, b.y, b.z, b.w};
        #pragma unroll
        for (int j = 0; j < 8; ++j) {
            const u32 hb = bf_rne(xv[j]);
            const float hf = __uint_as_float(hb << 16);
            Ahi[s][j] = (short)hb;
            Alo[s][j] = (short)bf_rne(xv[j] - hf);
        }
    }
    __syncthreads();

    f32x4 acc[8] = {};
    #pragma unroll
    for (int t = 0; t < 8; ++t) {
        #pragma unroll
        for (int s = 0; s < 2; ++s) {
            const s16x8 Bh = *(const s16x8*)&whi[((t * 2 + s) * 64 + lane) * 8];
            const s16x8 Bl = *(const s16x8*)&wlo[((t * 2 + s) * 64 + lane) * 8];
            acc[t] = __builtin_amdgcn_mfma_f32_16x16x32_bf16(Ahi[s], Bh, acc[t], 0, 0, 0);
            acc[t] = __builtin_amdgcn_mfma_f32_16x16x32_bf16(Alo[s], Bh, acc[t], 0, 0, 0);
            acc[t] = __builtin_amdgcn_mfma_f32_16x16x32_bf16(Ahi[s], Bl, acc[t], 0, 0, 0);
        }
    }

    float bias[8], gam[8], bet[8];
    #pragma unroll
    for (int t = 0; t < 8; ++t) {
        const int h = t * 16 + m;
        bias[t] = bp[h];
        gam[t]  = gp[h];
        bet[t]  = betap[h];
    }
    #pragma unroll
    for (int t = 0; t < 8; ++t)
        #pragma unroll
        for (int r = 0; r < 4; ++r)
            acc[t][r] += bias[t];

    float sum[4] = {0, 0, 0, 0}, sq[4] = {0, 0, 0, 0};
    #pragma unroll
    for (int t = 0; t < 8; ++t)
        #pragma unroll
        for (int r = 0; r < 4; ++r) {
            const float v = acc[t][r];
            sum[r] += v; sq[r] += v * v;
        }
    #pragma unroll
    for (int r = 0; r < 4; ++r) {
        #pragma unroll
        for (int o = 1; o < 16; o <<= 1) {
            sum[r] += __shfl_xor(sum[r], o);
            sq[r]  += __shfl_xor(sq[r],  o);
        }
    }
    float mu[4], rs[4];
    #pragma unroll
    for (int r = 0; r < 4; ++r) {
        mu[r] = sum[r] * (1.0f / 128.0f);
        const float var = sq[r] * (1.0f / 128.0f) - mu[r] * mu[r];
        rs[r] = rsqrtf(var + EPS);
    }

    int mk[4];
    #pragma unroll
    for (int r = 0; r < 4; ++r) mk[r] = maskp[rb + q * 4 + r];

    float gmax[8];
    #pragma unroll
    for (int t = 0; t < 8; ++t) {
        float gm = 0.0f;
        #pragma unroll
        for (int r = 0; r < 4; ++r) {
            float y = (acc[t][r] - mu[r]) * rs[r] * gam[t] + bet[t];
            y = fmaxf(y, 0.0f);
            acc[t][r] = y;
            if (mk[r] != 0) gm = fmaxf(gm, y);
        }
        gmax[t] = gm;
    }

    __syncthreads();
    #pragma unroll
    for (int t = 0; t < 8; ++t)
        #pragma unroll
        for (int r = 0; r < 4; ++r)
            tb[(w * 16 + q * 4 + r) * 132 + t * 16 + m] = acc[t][r];
    __syncthreads();

    {
        const int rr0 = tid >> 5;
        const int c   = tid & 31;
        const size_t growbase = (size_t)n * L + chunk * 64;
        #pragma unroll
        for (int i = 0; i < 8; ++i) {
            const int rr = i * 8 + rr0;
            const float4 v = *(const float4*)&tb[rr * 132 + c * 4];
            *(float4*)(outp + (growbase + rr) * (2 * H) + c * 4) = v;
        }
    }

    #pragma unroll
    for (int t = 0; t < 8; ++t) {
        float gm = gmax[t];
        gm = fmaxf(gm, __shfl_xor(gm, 16));
        gm = fmaxf(gm, __shfl_xor(gm, 32));
        if (q == 0) gsh[w * H + t * 16 + m] = gm;
    }
    __syncthreads();
    if (tid < H) {
        const float mx = fmaxf(fmaxf(gsh[0 * H + tid], gsh[1 * H + tid]),
                               fmaxf(gsh[2 * H + tid], gsh[3 * H + tid]));
        atomicMax((u32*)(outp + NTOT + (size_t)n * H + tid), __float_as_uint(mx));
    }
}

__global__ __launch_bounds__(256)
void k2_bcast(float* __restrict__ outp)
{
    const int bx  = blockIdx.x;
    const int n   = bx >> 3;
    const int c2  = bx & 7;
    const int tid = threadIdx.x;
    const int tc  = tid & 31;
    const int tr  = tid >> 5;
    const int h0  = tc * 4;

    const float4 g4 = *(const float4*)(outp + NTOT + (size_t)n * H + h0);

    #pragma unroll
    for (int ri = 0; ri < 8; ++ri) {
        const int l = c2 * 64 + tr * 8 + ri;
        *(float4*)(outp + ((size_t)n * L + l) * (2 * H) + H + h0) = g4;
    }
}

extern "C" void kernel_launch(void* const* d_in, const int* in_sizes, int n_in,
                              void* d_out, int out_size, void* d_ws, size_t ws_size,
                              hipStream_t stream)
{
    (void)in_sizes; (void)n_in; (void)out_size;
    const float* x     = (const float*)d_in[0];
    const int*   mask  = (const int*)d_in[1];
    const float* W     = (const float*)d_in[2];
    const float* b     = (const float*)d_in[3];
    const float* gamma = (const float*)d_in[4];
    const float* beta  = (const float*)d_in[5];
    float* out = (float*)d_out;

    if (d_ws != nullptr && ws_size >= WS_NEED) {
        kp_prep<<<dim3(8), dim3(256), 0, stream>>>(W, out, (char*)d_ws);
        k1_main<<<dim3(NB * 8), dim3(256), 0, stream>>>(
            x, mask, b, gamma, beta, out, (char*)d_ws);
    } else {
        k0_init<<<dim3((NB * H + 255) / 256), dim3(256), 0, stream>>>(out);
        k1_gemm_ln<<<dim3(NB * 8), dim3(256), 0, stream>>>(
            x, mask, W, b, gamma, beta, out);
        k2_bcast<<<dim3(NB * 8), dim3(256), 0, stream>>>(out);
    }
}